// Round 6
// baseline (645.258 us; speedup 1.0000x reference)
//
#include <hip/hip_runtime.h>
#include <hip/hip_cooperative_groups.h>

namespace cg = cooperative_groups;

// Problem constants (fixed by the reference)
#define NGRAPH 16
#define NPG    4096
#define KCL    64
#define DF     128
#define NTOT   65536
#define NEDGE  1048576

// output layout (floats)
//   out[0,131072) | out_adj[131072,196608) | link 196608 | ent 196609
//   batch[196610,197634) | batch_ptr[197634,197651)

// ws layout (bytes) — everything plain-stored, nothing needs zeroing
#define WS_CLUS   0         // u8[65536]
#define WS_HIST   65536     // int[256][64]   per-P1-block histograms
#define WS_BASE   131072    // int[256][64]   per-P1-block scatter bases
#define WS_CNT    196608    // int[1024]
#define WS_START  200704    // int[1024]
#define WS_S2     204800    // float[16]
#define WS_CROSS  204928    // float[256]
#define WS_ASQ    205952    // float[256]
#define WS_ORDER  206976    // u16[65536]
#define WS_ADJP   338048    // float[256][4096]

union Smem {
    struct {                                  // P2 edge (20,608 B)
        float adj[KCL * KCL];
        unsigned char cl[NPG];
        float redc[16], redq[16];
    } edge;
    struct { int offs[64]; } scat;            // P3
    struct {                                  // P4 pool (49,216 B — max)
        unsigned short ord[4][NPG];
        float4 part[4][8][32];
        float links[16];
    } pool;
};

__global__ __launch_bounds__(1024, 4) void fused_kernel(
    const float* __restrict__ x, const float* __restrict__ W,
    const float* __restrict__ bias, const float* __restrict__ ew,
    const float* __restrict__ gum, const int* __restrict__ ei,
    float* __restrict__ out, char* __restrict__ wsb)
{
    __shared__ Smem sm;
    __shared__ int sh_hist[64];
    __shared__ int sh_pre[16 * 64];
    cg::grid_group grid = cg::this_grid();

    const int tid  = threadIdx.x;
    const int wave = tid >> 6;
    const int lane = tid & 63;
    const int blk  = blockIdx.x;

    //================ P1: assign (lane = cluster) + per-block hist ==========
    {
        if (tid < 64) sh_hist[tid] = 0;
        __syncthreads();

        const int k  = lane;
        const int wu = __builtin_amdgcn_readfirstlane(wave);   // wave-uniform
        const int nb = blk * 256 + (wu << 4);                  // wave's 16 nodes

        float accv[16];
        const float bb = bias[k];
        #pragma unroll
        for (int j = 0; j < 16; ++j) accv[j] = bb;

        #pragma unroll
        for (int h = 0; h < 2; ++h) {
            float wreg[64];                    // W[d][k] column chunk, reused x16
            #pragma unroll
            for (int d = 0; d < 64; ++d)
                wreg[d] = W[(((h << 6) + d) << 6) + k];
            #pragma unroll 2
            for (int j = 0; j < 16; ++j) {
                const float* xr = x + ((size_t)(nb + j) << 7) + (h << 6); // uniform -> s_load
                float a0 = 0.f, a1 = 0.f;
                #pragma unroll
                for (int d = 0; d < 64; d += 2) {
                    a0 = fmaf(xr[d],     wreg[d],     a0);
                    a1 = fmaf(xr[d + 1], wreg[d + 1], a1);
                }
                accv[j] += a0 + a1;
            }
        }

        unsigned char* clus = (unsigned char*)(wsb + WS_CLUS);
        for (int j = 0; j < 16; ++j) {
            const int nn = nb + j;
            float u = gum[((size_t)nn << 6) + k];
            float v = accv[j] - __logf(-__logf(u));   // logits + gumbel
            int  bi = k;
            #pragma unroll
            for (int off = 1; off < 64; off <<= 1) {  // (max, min-index) butterfly
                float ov = __shfl_xor(v, off);
                int   oi = __shfl_xor(bi, off);
                if (ov > v || (ov == v && oi < bi)) { v = ov; bi = oi; }
            }
            if (k == 0) {
                clus[nn] = (unsigned char)bi;
                atomicAdd(&sh_hist[bi], 1);
            }
        }
        __syncthreads();
        if (tid < 64) ((int*)(wsb + WS_HIST))[(blk << 6) + tid] = sh_hist[tid];
    }

    __threadfence();
    grid.sync();

    //================ P2: scan (blk<16, wave 0) + edge slice (all) ==========
    if (blk < 16 && tid < 64) {
        const int bg = blk, k = tid;
        const int* hist_pb = (const int*)(wsb + WS_HIST);
        int run = 0;
        #pragma unroll
        for (int j = 0; j < 16; ++j) {
            sh_pre[(j << 6) + k] = run;
            run += hist_pb[(((bg << 4) + j) << 6) + k];
        }
        ((int*)(wsb + WS_CNT))[(bg << 6) + k] = run;
        int inc = run;                          // exclusive scan over k
        #pragma unroll
        for (int off = 1; off < 64; off <<= 1) {
            int t = __shfl_up(inc, off);
            if (k >= off) inc += t;
        }
        const int excl = inc - run;
        ((int*)(wsb + WS_START))[(bg << 6) + k] = excl;
        float fc = (float)run;
        float s2 = fc * fc;
        #pragma unroll
        for (int off = 32; off > 0; off >>= 1) s2 += __shfl_down(s2, off);
        if (k == 0) ((float*)(wsb + WS_S2))[bg] = s2;
        int* base_pb = (int*)(wsb + WS_BASE);
        #pragma unroll
        for (int j = 0; j < 16; ++j)
            base_pb[(((bg << 4) + j) << 6) + k] = excl + sh_pre[(j << 6) + k];
    }
    {
        const int bg = blk >> 4;
        ((float4*)sm.edge.adj)[tid] = make_float4(0.f, 0.f, 0.f, 0.f);
        ((int*)sm.edge.cl)[tid] = ((const int*)(wsb + WS_CLUS + ((size_t)bg << 12)))[tid];
        __syncthreads();
        const int e0 = blk << 12;               // slice = 4096 contiguous edges
        float csum = 0.f, qsum = 0.f;
        #pragma unroll
        for (int it = 0; it < 4; ++it) {
            const int e = e0 + (it << 10) + tid;
            const int s = ei[e]         & (NPG - 1);
            const int d = ei[NEDGE + e] & (NPG - 1);
            const float w = ew[e];
            const int ks = sm.edge.cl[s], kd = sm.edge.cl[d];
            atomicAdd(&sm.edge.adj[(ks << 6) + kd], w);
            csum += (ks == kd) ? w : 0.f;
            qsum += w * w;
        }
        #pragma unroll
        for (int off = 32; off > 0; off >>= 1) {
            csum += __shfl_down(csum, off);
            qsum += __shfl_down(qsum, off);
        }
        if (lane == 0) { sm.edge.redc[wave] = csum; sm.edge.redq[wave] = qsum; }
        __syncthreads();
        if (tid == 0) {
            float cs = 0.f, qs = 0.f;
            #pragma unroll
            for (int i = 0; i < 16; ++i) { cs += sm.edge.redc[i]; qs += sm.edge.redq[i]; }
            ((float*)(wsb + WS_CROSS))[blk] = cs;
            ((float*)(wsb + WS_ASQ))[blk]   = qs;
        }
        ((float4*)(wsb + WS_ADJP + ((size_t)blk << 14)))[tid] = ((const float4*)sm.edge.adj)[tid];
    }

    __threadfence();
    grid.sync();

    //================ P3: scatter cluster-sorted order ======================
    {
        if (tid < 64) sm.scat.offs[tid] = ((const int*)(wsb + WS_BASE))[(blk << 6) + tid];
        __syncthreads();
        if (tid < 256) {
            const int bg = blk >> 4;
            const int c = ((const unsigned char*)(wsb + WS_CLUS))[blk * 256 + tid];
            const int p = atomicAdd(&sm.scat.offs[c], 1);
            ((unsigned short*)(wsb + WS_ORDER))[(bg << 12) + p] =
                (unsigned short)(((blk & 15) << 8) + tid);
        }
    }

    __threadfence();
    grid.sync();

    //================ P4: pool + adj-reduce + finalize ======================
    {
        const int g = tid >> 8, lt = tid & 255;
        const int cc = (blk << 2) + g;          // (graph, cluster) id
        const int bg = cc >> 6;
        const int cnt   = ((const int*)(wsb + WS_CNT))[cc];
        const int start = ((const int*)(wsb + WS_START))[cc];
        const unsigned short* order = (const unsigned short*)(wsb + WS_ORDER);
        for (int i = lt; i < cnt; i += 256)
            sm.pool.ord[g][i] = order[(bg << 12) + start + i];
        __syncthreads();
        const int grp = lt >> 5, l32 = lt & 31;
        float4 acc = {0.f, 0.f, 0.f, 0.f};
        for (int i = grp; i < cnt; i += 8) {
            const float4* row =
                (const float4*)(x + (((size_t)(bg << 12) + sm.pool.ord[g][i]) << 7));
            float4 v = row[l32];
            acc.x += v.x; acc.y += v.y; acc.z += v.z; acc.w += v.w;
        }
        sm.pool.part[g][grp][l32] = acc;
        __syncthreads();
        if (grp == 0) {
            float4 s = sm.pool.part[g][0][l32];
            #pragma unroll
            for (int q = 1; q < 8; ++q) {
                float4 p = sm.pool.part[g][q][l32];
                s.x += p.x; s.y += p.y; s.z += p.z; s.w += p.w;
            }
            ((float4*)(out + ((size_t)cc << 7)))[l32] = s;
        }
    }
    if (tid < 256) {                            // adj reduce: 256 cells/block
        const int c = (blk << 8) + tid;
        const int bg2 = c >> 12, j = c & 4095;
        const float* adjp = (const float*)(wsb + WS_ADJP);
        float s = 0.f;
        #pragma unroll
        for (int sl = 0; sl < 16; ++sl)
            s += adjp[((((bg2 << 4) + sl)) << 12) + j];
        out[131072 + c] = s;
    }
    if (blk == 0) {                             // losses + constants
        __syncthreads();
        if (tid < 16) {
            const float* crossp = (const float*)(wsb + WS_CROSS);
            const float* asqp   = (const float*)(wsb + WS_ASQ);
            float cs = 0.f, as = 0.f;
            #pragma unroll
            for (int sl = 0; sl < 16; ++sl) {
                cs += crossp[(tid << 4) + sl];
                as += asqp[(tid << 4) + sl];
            }
            const float s2 = ((const float*)(wsb + WS_S2))[tid];
            sm.pool.links[tid] = sqrtf(fmaxf(as - 2.f * cs + s2, 0.f)) * (1.f / 65536.f);
        }
        __syncthreads();
        if (tid == 0) {
            float m = 0.f;
            #pragma unroll
            for (int i = 0; i < 16; ++i) m += sm.pool.links[i];
            out[196608] = m * (1.f / 16.f);     // link_loss
            out[196609] = 0.f;                  // entropy_loss (exact 0, one-hot)
        }
        out[196610 + tid] = (float)(tid >> 6);              // batch
        if (tid < 17) out[197634 + tid] = (float)(tid << 6); // batch_ptr_out
    }
}

//===========================================================================
// Fallback path — the R4 five-kernel pipeline (proven, 136 µs), sharing ws.
//===========================================================================
__global__ __launch_bounds__(256) void fb_assign(
    const float* __restrict__ x, const float* __restrict__ W,
    const float* __restrict__ bias, const float* __restrict__ gum,
    unsigned char* __restrict__ clus)
{
    __shared__ __align__(16) float xs[64 * 132];
    __shared__ float cand_v[4][64];
    __shared__ int   cand_k[4][64];
    const int tid = threadIdx.x, wave = tid >> 6, lane = tid & 63;
    const int n0 = blockIdx.x * 64;
    {
        const float4* xg = (const float4*)(x + (size_t)n0 * DF);
        #pragma unroll
        for (int i = 0; i < 8; ++i) {
            int j4 = tid + i * 256; int j = j4 << 2;
            float4 v = xg[j4];
            *(float4*)&xs[(j >> 7) * 132 + (j & 127)] = v;
        }
    }
    __syncthreads();
    const int k0 = __builtin_amdgcn_readfirstlane(wave << 4);
    float acc[16];
    #pragma unroll
    for (int kk = 0; kk < 16; ++kk) acc[kk] = bias[k0 + kk];
    #pragma unroll 4
    for (int dc = 0; dc < 32; ++dc) {
        float4 xv = *(const float4*)&xs[lane * 132 + (dc << 2)];
        const float* wp = W + (dc << 8) + k0;
        #pragma unroll
        for (int kk = 0; kk < 16; ++kk) {
            float a = acc[kk];
            a = fmaf(xv.x, wp[kk],        a);
            a = fmaf(xv.y, wp[64  + kk],  a);
            a = fmaf(xv.z, wp[128 + kk],  a);
            a = fmaf(xv.w, wp[192 + kk],  a);
            acc[kk] = a;
        }
    }
    const float* gp = gum + ((size_t)(n0 + lane) << 6) + k0;
    float best = -3.4e38f; int bestk = k0;
    #pragma unroll
    for (int q = 0; q < 4; ++q) {
        float4 u = *(const float4*)(gp + (q << 2));
        float uv[4] = {u.x, u.y, u.z, u.w};
        #pragma unroll
        for (int r = 0; r < 4; ++r) {
            float g = -__logf(-__logf(uv[r]));
            float v = acc[(q << 2) + r] + g;
            if (v > best) { best = v; bestk = k0 + (q << 2) + r; }
        }
    }
    cand_v[wave][lane] = best;
    cand_k[wave][lane] = bestk;
    __syncthreads();
    if (tid < 64) {
        float bv = cand_v[0][tid]; int bk = cand_k[0][tid];
        #pragma unroll
        for (int w2 = 1; w2 < 4; ++w2) {
            float v = cand_v[w2][tid];
            if (v > bv) { bv = v; bk = cand_k[w2][tid]; }
        }
        clus[n0 + tid] = (unsigned char)bk;
    }
}

__global__ __launch_bounds__(1024) void fb_sort(
    const unsigned char* __restrict__ clus,
    int* __restrict__ counts, int* __restrict__ starts,
    unsigned short* __restrict__ order)
{
    __shared__ int hist[KCL];
    __shared__ int offs[KCL];
    const int tid = threadIdx.x, bg = blockIdx.x;
    if (tid < KCL) hist[tid] = 0;
    __syncthreads();
    unsigned char c[4];
    #pragma unroll
    for (int i = 0; i < 4; ++i) {
        c[i] = clus[(bg << 12) + tid + (i << 10)];
        atomicAdd(&hist[c[i]], 1);
    }
    __syncthreads();
    if (tid < KCL) {
        int v = hist[tid], inc = v;
        #pragma unroll
        for (int off = 1; off < 64; off <<= 1) {
            int t = __shfl_up(inc, off);
            if (tid >= off) inc += t;
        }
        int excl = inc - v;
        offs[tid] = excl;
        counts[(bg << 6) + tid] = v;
        starts[(bg << 6) + tid] = excl;
    }
    __syncthreads();
    #pragma unroll
    for (int i = 0; i < 4; ++i) {
        int p = atomicAdd(&offs[c[i]], 1);
        order[(bg << 12) + p] = (unsigned short)(tid + (i << 10));
    }
}

__global__ __launch_bounds__(256) void fb_pool(
    const float* __restrict__ x, const unsigned short* __restrict__ order,
    const int* __restrict__ counts, const int* __restrict__ starts,
    float* __restrict__ out)
{
    __shared__ unsigned short ord[NPG];
    __shared__ float4 part[8][32];
    const int tid = threadIdx.x, bg = blockIdx.x >> 6, k = blockIdx.x & 63;
    const int cnt = counts[(bg << 6) + k], start = starts[(bg << 6) + k];
    for (int i = tid; i < cnt; i += 256)
        ord[i] = order[(bg << 12) + start + i];
    __syncthreads();
    const int grp = tid >> 5, l32 = tid & 31;
    float4 acc = {0.f, 0.f, 0.f, 0.f};
    for (int i = grp; i < cnt; i += 8) {
        const float4* row = (const float4*)(x + ((size_t)(bg << 12) + ord[i]) * DF);
        float4 v = row[l32];
        acc.x += v.x; acc.y += v.y; acc.z += v.z; acc.w += v.w;
    }
    part[grp][l32] = acc;
    __syncthreads();
    if (grp == 0) {
        float4 s = part[0][l32];
        #pragma unroll
        for (int g = 1; g < 8; ++g) {
            float4 p = part[g][l32];
            s.x += p.x; s.y += p.y; s.z += p.z; s.w += p.w;
        }
        ((float4*)(out + (size_t)(bg << 13) + (k << 7)))[l32] = s;
    }
}

__global__ __launch_bounds__(512) void fb_edge(
    const int* __restrict__ ei, const float* __restrict__ ew,
    const unsigned char* __restrict__ clus,
    float* __restrict__ partials, float* __restrict__ crossp,
    float* __restrict__ asqp)
{
    __shared__ float adj[KCL * KCL];
    __shared__ unsigned char cl[NPG];
    __shared__ float redc[8], redq[8];
    const int tid = threadIdx.x, bg = blockIdx.x >> 4;
    #pragma unroll
    for (int i = 0; i < 8; ++i) adj[tid + i * 512] = 0.0f;
    #pragma unroll
    for (int i = 0; i < 2; ++i)
        ((int*)cl)[tid + i * 512] = ((const int*)(clus + (size_t)bg * NPG))[tid + i * 512];
    __syncthreads();
    const int e0 = blockIdx.x * 4096;
    float csum = 0.f, qsum = 0.f;
    #pragma unroll
    for (int it = 0; it < 8; ++it) {
        const int e = e0 + it * 512 + tid;
        const int s = ei[e] & (NPG - 1);
        const int d = ei[NEDGE + e] & (NPG - 1);
        const float w = ew[e];
        const int ks = cl[s], kd = cl[d];
        atomicAdd(&adj[(ks << 6) + kd], w);
        csum += (ks == kd) ? w : 0.f;
        qsum += w * w;
    }
    #pragma unroll
    for (int off = 32; off > 0; off >>= 1) {
        csum += __shfl_down(csum, off);
        qsum += __shfl_down(qsum, off);
    }
    const int lane = tid & 63, wv = tid >> 6;
    if (lane == 0) { redc[wv] = csum; redq[wv] = qsum; }
    __syncthreads();
    if (tid == 0) {
        float cs = 0.f, qs = 0.f;
        #pragma unroll
        for (int i = 0; i < 8; ++i) { cs += redc[i]; qs += redq[i]; }
        crossp[blockIdx.x] = cs;
        asqp[blockIdx.x]   = qs;
    }
    float4* dst = (float4*)(partials + (size_t)blockIdx.x * 4096);
    const float4* src = (const float4*)adj;
    dst[tid] = src[tid];
    dst[tid + 512] = src[tid + 512];
}

__global__ __launch_bounds__(1024) void fb_reduce_finalize(
    const float* __restrict__ partials, const float* __restrict__ crossp,
    const float* __restrict__ asqp, const int* __restrict__ counts,
    float* __restrict__ out)
{
    const int tid = threadIdx.x;
    if (blockIdx.x < 64) {
        const int cell = blockIdx.x * 1024 + tid;
        const int bg = cell >> 12, j = cell & 4095;
        float s = 0.f;
        #pragma unroll
        for (int sl = 0; sl < 16; ++sl)
            s += partials[(size_t)((bg << 4) + sl) * 4096 + j];
        out[131072 + cell] = s;
        return;
    }
    __shared__ float links[16];
    const int wv = tid >> 6, lane = tid & 63;
    float c = (float)counts[(wv << 6) + lane];
    float s2 = c * c;
    #pragma unroll
    for (int off = 32; off > 0; off >>= 1) s2 += __shfl_down(s2, off);
    float cp = (lane < 16) ? crossp[(wv << 4) + lane] : 0.f;
    float ap = (lane < 16) ? asqp[(wv << 4) + lane]   : 0.f;
    #pragma unroll
    for (int off = 8; off > 0; off >>= 1) {
        cp += __shfl_down(cp, off);
        ap += __shfl_down(ap, off);
    }
    if (lane == 0) links[wv] = sqrtf(fmaxf(ap - 2.f * cp + s2, 0.f)) * (1.f / 65536.f);
    __syncthreads();
    if (tid == 0) {
        float m = 0.f;
        #pragma unroll
        for (int i = 0; i < 16; ++i) m += links[i];
        out[196608] = m * (1.f / 16.f);
        out[196609] = 0.f;
    }
    out[196610 + tid] = (float)(tid >> 6);
    if (tid < 17) out[197634 + tid] = (float)(tid << 6);
}

extern "C" void kernel_launch(void* const* d_in, const int* in_sizes, int n_in,
                              void* d_out, int out_size, void* d_ws, size_t ws_size,
                              hipStream_t stream) {
    const float* x    = (const float*)d_in[0];
    const float* W    = (const float*)d_in[1];
    const float* bias = (const float*)d_in[2];
    const float* ew   = (const float*)d_in[3];
    const float* gum  = (const float*)d_in[4];
    const int*   ei   = (const int*)  d_in[5];
    // d_in[6] = batch_ptr (int64) — unused, graphs are equal-sized

    float* out = (float*)d_out;
    char*  wsb = (char*)d_ws;

    void* args[] = {&x, &W, &bias, &ew, &gum, &ei, &out, &wsb};
    hipError_t err = hipLaunchCooperativeKernel(
        (const void*)fused_kernel, dim3(256), dim3(1024), args, 0, stream);

    if (err != hipSuccess) {
        // Fallback: proven 5-kernel pipeline, same math, same ws buffers.
        unsigned char*  clus   = (unsigned char*) (wsb + WS_CLUS);
        int*            counts = (int*)           (wsb + WS_CNT);
        int*            starts = (int*)           (wsb + WS_START);
        float*          crossp = (float*)         (wsb + WS_CROSS);
        float*          asqp   = (float*)         (wsb + WS_ASQ);
        unsigned short* order  = (unsigned short*)(wsb + WS_ORDER);
        float*          adjp   = (float*)         (wsb + WS_ADJP);

        fb_assign<<<NTOT / 64, 256, 0, stream>>>(x, W, bias, gum, clus);
        fb_sort<<<NGRAPH, 1024, 0, stream>>>(clus, counts, starts, order);
        fb_pool<<<NGRAPH * KCL, 256, 0, stream>>>(x, order, counts, starts, out);
        fb_edge<<<NGRAPH * 16, 512, 0, stream>>>(ei, ew, clus, adjp, crossp, asqp);
        fb_reduce_finalize<<<65, 1024, 0, stream>>>(adjp, crossp, asqp, counts, out);
    }
}

// Round 7
// 475.720 us; speedup vs baseline: 1.3564x; 1.3564x over previous
//
#include <hip/hip_runtime.h>
#include <hip/hip_cooperative_groups.h>

namespace cg = cooperative_groups;

// Problem constants (fixed by the reference)
#define NGRAPH 16
#define NPG    4096
#define KCL    64
#define DF     128
#define NTOT   65536
#define NEDGE  1048576

// output layout (floats)
//   out[0,131072) | out_adj[131072,196608) | link 196608 | ent 196609
//   batch[196610,197634) | batch_ptr[197634,197651)

// ws layout (bytes) — everything plain-stored, nothing needs zeroing
#define WS_CLUS   0         // u8[65536]
#define WS_HIST   65536     // int[256][64]   per-block histograms (256 nodes/block)
#define WS_BASE   131072    // int[256][64]   per-block scatter bases
#define WS_CNT    196608    // int[1024]
#define WS_START  200704    // int[1024]
#define WS_S2     204800    // float[16]
#define WS_CROSS  204928    // float[256]
#define WS_ASQ    205952    // float[256]
#define WS_ORDER  206976    // u16[65536]
#define WS_ADJP   338048    // float[256][4096]

union Smem {
    struct {                                  // P1 assign (41,984 B)
        float xs[64 * 132];                   // 64-node tile, pad 132
        float cand_v[16][64];
        int   cand_k[16][64];
    } p1;
    struct {                                  // P2 edge (20,608 B)
        float adj[KCL * KCL];
        unsigned char cl[NPG];
        float redc[16], redq[16];
    } edge;
    struct { int offs[64]; } scat;            // P3
    struct {                                  // P4 pool (49,216 B — max)
        unsigned short ord[4][NPG];
        float4 part[4][8][32];
        float links[16];
    } pool;
};

__global__ __launch_bounds__(1024, 4) void fused_kernel(
    const float* __restrict__ x, const float* __restrict__ W,
    const float* __restrict__ bias, const float* __restrict__ ew,
    const float* __restrict__ gum, const int* __restrict__ ei,
    float* __restrict__ out, char* __restrict__ wsb)
{
    __shared__ Smem sm;
    __shared__ int sh_hist[64];
    __shared__ int sh_pre[16 * 64];
    cg::grid_group grid = cg::this_grid();

    const int tid  = threadIdx.x;
    const int wave = tid >> 6;
    const int lane = tid & 63;
    const int blk  = blockIdx.x;

    //================ P1: assign — 4 LDS tiles of 64 nodes ==================
    // 16 waves x 4 clusters each; lane = node; acc[4] per lane (no spill).
    {
        if (tid < 64) sh_hist[tid] = 0;
        unsigned char* clus = (unsigned char*)(wsb + WS_CLUS);
        const int k0 = __builtin_amdgcn_readfirstlane(wave << 2);  // wave-uniform

        for (int t = 0; t < 4; ++t) {
            __syncthreads();                 // protect xs/cand reuse (+hist init)
            const int n0 = blk * 256 + t * 64;
            const float4* xg = (const float4*)(x + (size_t)n0 * DF);
            #pragma unroll
            for (int i = 0; i < 2; ++i) {
                int j4 = tid + (i << 10); int j = j4 << 2;
                *(float4*)&sm.p1.xs[(j >> 7) * 132 + (j & 127)] = xg[j4];
            }
            __syncthreads();

            float acc[4] = {bias[k0], bias[k0 + 1], bias[k0 + 2], bias[k0 + 3]};
            #pragma unroll 4
            for (int dc = 0; dc < 32; ++dc) {
                float4 xv = *(const float4*)&sm.p1.xs[lane * 132 + (dc << 2)];
                const float* wp = W + (dc << 8) + k0;   // wave-uniform -> s_load
                #pragma unroll
                for (int r = 0; r < 4; ++r) {
                    float a = acc[r];
                    a = fmaf(xv.x, wp[r],        a);
                    a = fmaf(xv.y, wp[64  + r],  a);
                    a = fmaf(xv.z, wp[128 + r],  a);
                    a = fmaf(xv.w, wp[192 + r],  a);
                    acc[r] = a;
                }
            }

            // gumbel + per-wave argmax over its 4 k's (ascending => first-max)
            float4 u = *(const float4*)(gum + ((size_t)(n0 + lane) << 6) + k0);
            float uv[4] = {u.x, u.y, u.z, u.w};
            float best = -3.4e38f; int bestk = k0;
            #pragma unroll
            for (int r = 0; r < 4; ++r) {
                float v = acc[r] - __logf(-__logf(uv[r]));
                if (v > best) { best = v; bestk = k0 + r; }
            }
            sm.p1.cand_v[wave][lane] = best;
            sm.p1.cand_k[wave][lane] = bestk;
            __syncthreads();

            // combine 16 waves (k-chunks ascending => global first-max)
            if (tid < 64) {
                float bv = sm.p1.cand_v[0][tid]; int bk = sm.p1.cand_k[0][tid];
                #pragma unroll
                for (int w2 = 1; w2 < 16; ++w2) {
                    float v = sm.p1.cand_v[w2][tid];
                    if (v > bv) { bv = v; bk = sm.p1.cand_k[w2][tid]; }
                }
                clus[n0 + tid] = (unsigned char)bk;
                atomicAdd(&sh_hist[bk], 1);
            }
        }
        __syncthreads();
        if (tid < 64) ((int*)(wsb + WS_HIST))[(blk << 6) + tid] = sh_hist[tid];
    }

    __threadfence();
    grid.sync();

    //================ P2: scan (blk<16, wave 0) + edge slice (all) ==========
    if (blk < 16 && tid < 64) {
        const int bg = blk, k = tid;
        const int* hist_pb = (const int*)(wsb + WS_HIST);
        int run = 0;
        #pragma unroll
        for (int j = 0; j < 16; ++j) {
            sh_pre[(j << 6) + k] = run;
            run += hist_pb[(((bg << 4) + j) << 6) + k];
        }
        ((int*)(wsb + WS_CNT))[(bg << 6) + k] = run;
        int inc = run;                          // exclusive scan over k
        #pragma unroll
        for (int off = 1; off < 64; off <<= 1) {
            int t = __shfl_up(inc, off);
            if (k >= off) inc += t;
        }
        const int excl = inc - run;
        ((int*)(wsb + WS_START))[(bg << 6) + k] = excl;
        float fc = (float)run;
        float s2 = fc * fc;
        #pragma unroll
        for (int off = 32; off > 0; off >>= 1) s2 += __shfl_down(s2, off);
        if (k == 0) ((float*)(wsb + WS_S2))[bg] = s2;
        int* base_pb = (int*)(wsb + WS_BASE);
        #pragma unroll
        for (int j = 0; j < 16; ++j)
            base_pb[(((bg << 4) + j) << 6) + k] = excl + sh_pre[(j << 6) + k];
    }
    {
        const int bg = blk >> 4;
        ((float4*)sm.edge.adj)[tid] = make_float4(0.f, 0.f, 0.f, 0.f);
        ((int*)sm.edge.cl)[tid] = ((const int*)(wsb + WS_CLUS + ((size_t)bg << 12)))[tid];
        __syncthreads();
        const int e0 = blk << 12;               // slice = 4096 contiguous edges
        float csum = 0.f, qsum = 0.f;
        #pragma unroll
        for (int it = 0; it < 4; ++it) {
            const int e = e0 + (it << 10) + tid;
            const int s = ei[e]         & (NPG - 1);
            const int d = ei[NEDGE + e] & (NPG - 1);
            const float w = ew[e];
            const int ks = sm.edge.cl[s], kd = sm.edge.cl[d];
            atomicAdd(&sm.edge.adj[(ks << 6) + kd], w);
            csum += (ks == kd) ? w : 0.f;
            qsum += w * w;
        }
        #pragma unroll
        for (int off = 32; off > 0; off >>= 1) {
            csum += __shfl_down(csum, off);
            qsum += __shfl_down(qsum, off);
        }
        if (lane == 0) { sm.edge.redc[wave] = csum; sm.edge.redq[wave] = qsum; }
        __syncthreads();
        if (tid == 0) {
            float cs = 0.f, qs = 0.f;
            #pragma unroll
            for (int i = 0; i < 16; ++i) { cs += sm.edge.redc[i]; qs += sm.edge.redq[i]; }
            ((float*)(wsb + WS_CROSS))[blk] = cs;
            ((float*)(wsb + WS_ASQ))[blk]   = qs;
        }
        ((float4*)(wsb + WS_ADJP + ((size_t)blk << 14)))[tid] = ((const float4*)sm.edge.adj)[tid];
    }

    __threadfence();
    grid.sync();

    //================ P3: scatter cluster-sorted order ======================
    {
        if (tid < 64) sm.scat.offs[tid] = ((const int*)(wsb + WS_BASE))[(blk << 6) + tid];
        __syncthreads();
        if (tid < 256) {
            const int bg = blk >> 4;
            const int c = ((const unsigned char*)(wsb + WS_CLUS))[blk * 256 + tid];
            const int p = atomicAdd(&sm.scat.offs[c], 1);
            ((unsigned short*)(wsb + WS_ORDER))[(bg << 12) + p] =
                (unsigned short)(((blk & 15) << 8) + tid);
        }
    }

    __threadfence();
    grid.sync();

    //================ P4: pool + adj-reduce + finalize ======================
    {
        const int g = tid >> 8, lt = tid & 255;
        const int cc = (blk << 2) + g;          // (graph, cluster) id
        const int bg = cc >> 6;
        const int cnt   = ((const int*)(wsb + WS_CNT))[cc];
        const int start = ((const int*)(wsb + WS_START))[cc];
        const unsigned short* order = (const unsigned short*)(wsb + WS_ORDER);
        for (int i = lt; i < cnt; i += 256)
            sm.pool.ord[g][i] = order[(bg << 12) + start + i];
        __syncthreads();
        const int grp = lt >> 5, l32 = lt & 31;
        float4 acc = {0.f, 0.f, 0.f, 0.f};
        for (int i = grp; i < cnt; i += 8) {
            const float4* row =
                (const float4*)(x + (((size_t)(bg << 12) + sm.pool.ord[g][i]) << 7));
            float4 v = row[l32];
            acc.x += v.x; acc.y += v.y; acc.z += v.z; acc.w += v.w;
        }
        sm.pool.part[g][grp][l32] = acc;
        __syncthreads();
        if (grp == 0) {
            float4 s = sm.pool.part[g][0][l32];
            #pragma unroll
            for (int q = 1; q < 8; ++q) {
                float4 p = sm.pool.part[g][q][l32];
                s.x += p.x; s.y += p.y; s.z += p.z; s.w += p.w;
            }
            ((float4*)(out + ((size_t)cc << 7)))[l32] = s;
        }
    }
    if (tid < 256) {                            // adj reduce: 256 cells/block
        const int c = (blk << 8) + tid;
        const int bg2 = c >> 12, j = c & 4095;
        const float* adjp = (const float*)(wsb + WS_ADJP);
        float s = 0.f;
        #pragma unroll
        for (int sl = 0; sl < 16; ++sl)
            s += adjp[((((bg2 << 4) + sl)) << 12) + j];
        out[131072 + c] = s;
    }
    if (blk == 0) {                             // losses + constants
        __syncthreads();
        if (tid < 16) {
            const float* crossp = (const float*)(wsb + WS_CROSS);
            const float* asqp   = (const float*)(wsb + WS_ASQ);
            float cs = 0.f, as = 0.f;
            #pragma unroll
            for (int sl = 0; sl < 16; ++sl) {
                cs += crossp[(tid << 4) + sl];
                as += asqp[(tid << 4) + sl];
            }
            const float s2 = ((const float*)(wsb + WS_S2))[tid];
            sm.pool.links[tid] = sqrtf(fmaxf(as - 2.f * cs + s2, 0.f)) * (1.f / 65536.f);
        }
        __syncthreads();
        if (tid == 0) {
            float m = 0.f;
            #pragma unroll
            for (int i = 0; i < 16; ++i) m += sm.pool.links[i];
            out[196608] = m * (1.f / 16.f);     // link_loss
            out[196609] = 0.f;                  // entropy_loss (exact 0, one-hot)
        }
        out[196610 + tid] = (float)(tid >> 6);              // batch
        if (tid < 17) out[197634 + tid] = (float)(tid << 6); // batch_ptr_out
    }
}

//===========================================================================
// Fallback path — the R4 five-kernel pipeline (proven, 136 µs), sharing ws.
//===========================================================================
__global__ __launch_bounds__(256) void fb_assign(
    const float* __restrict__ x, const float* __restrict__ W,
    const float* __restrict__ bias, const float* __restrict__ gum,
    unsigned char* __restrict__ clus)
{
    __shared__ __align__(16) float xs[64 * 132];
    __shared__ float cand_v[4][64];
    __shared__ int   cand_k[4][64];
    const int tid = threadIdx.x, wave = tid >> 6, lane = tid & 63;
    const int n0 = blockIdx.x * 64;
    {
        const float4* xg = (const float4*)(x + (size_t)n0 * DF);
        #pragma unroll
        for (int i = 0; i < 8; ++i) {
            int j4 = tid + i * 256; int j = j4 << 2;
            float4 v = xg[j4];
            *(float4*)&xs[(j >> 7) * 132 + (j & 127)] = v;
        }
    }
    __syncthreads();
    const int k0 = __builtin_amdgcn_readfirstlane(wave << 4);
    float acc[16];
    #pragma unroll
    for (int kk = 0; kk < 16; ++kk) acc[kk] = bias[k0 + kk];
    #pragma unroll 4
    for (int dc = 0; dc < 32; ++dc) {
        float4 xv = *(const float4*)&xs[lane * 132 + (dc << 2)];
        const float* wp = W + (dc << 8) + k0;
        #pragma unroll
        for (int kk = 0; kk < 16; ++kk) {
            float a = acc[kk];
            a = fmaf(xv.x, wp[kk],        a);
            a = fmaf(xv.y, wp[64  + kk],  a);
            a = fmaf(xv.z, wp[128 + kk],  a);
            a = fmaf(xv.w, wp[192 + kk],  a);
            acc[kk] = a;
        }
    }
    const float* gp = gum + ((size_t)(n0 + lane) << 6) + k0;
    float best = -3.4e38f; int bestk = k0;
    #pragma unroll
    for (int q = 0; q < 4; ++q) {
        float4 u = *(const float4*)(gp + (q << 2));
        float uv[4] = {u.x, u.y, u.z, u.w};
        #pragma unroll
        for (int r = 0; r < 4; ++r) {
            float g = -__logf(-__logf(uv[r]));
            float v = acc[(q << 2) + r] + g;
            if (v > best) { best = v; bestk = k0 + (q << 2) + r; }
        }
    }
    cand_v[wave][lane] = best;
    cand_k[wave][lane] = bestk;
    __syncthreads();
    if (tid < 64) {
        float bv = cand_v[0][tid]; int bk = cand_k[0][tid];
        #pragma unroll
        for (int w2 = 1; w2 < 4; ++w2) {
            float v = cand_v[w2][tid];
            if (v > bv) { bv = v; bk = cand_k[w2][tid]; }
        }
        clus[n0 + tid] = (unsigned char)bk;
    }
}

__global__ __launch_bounds__(1024) void fb_sort(
    const unsigned char* __restrict__ clus,
    int* __restrict__ counts, int* __restrict__ starts,
    unsigned short* __restrict__ order)
{
    __shared__ int hist[KCL];
    __shared__ int offs[KCL];
    const int tid = threadIdx.x, bg = blockIdx.x;
    if (tid < KCL) hist[tid] = 0;
    __syncthreads();
    unsigned char c[4];
    #pragma unroll
    for (int i = 0; i < 4; ++i) {
        c[i] = clus[(bg << 12) + tid + (i << 10)];
        atomicAdd(&hist[c[i]], 1);
    }
    __syncthreads();
    if (tid < KCL) {
        int v = hist[tid], inc = v;
        #pragma unroll
        for (int off = 1; off < 64; off <<= 1) {
            int t = __shfl_up(inc, off);
            if (tid >= off) inc += t;
        }
        int excl = inc - v;
        offs[tid] = excl;
        counts[(bg << 6) + tid] = v;
        starts[(bg << 6) + tid] = excl;
    }
    __syncthreads();
    #pragma unroll
    for (int i = 0; i < 4; ++i) {
        int p = atomicAdd(&offs[c[i]], 1);
        order[(bg << 12) + p] = (unsigned short)(tid + (i << 10));
    }
}

__global__ __launch_bounds__(256) void fb_pool(
    const float* __restrict__ x, const unsigned short* __restrict__ order,
    const int* __restrict__ counts, const int* __restrict__ starts,
    float* __restrict__ out)
{
    __shared__ unsigned short ord[NPG];
    __shared__ float4 part[8][32];
    const int tid = threadIdx.x, bg = blockIdx.x >> 6, k = blockIdx.x & 63;
    const int cnt = counts[(bg << 6) + k], start = starts[(bg << 6) + k];
    for (int i = tid; i < cnt; i += 256)
        ord[i] = order[(bg << 12) + start + i];
    __syncthreads();
    const int grp = tid >> 5, l32 = tid & 31;
    float4 acc = {0.f, 0.f, 0.f, 0.f};
    for (int i = grp; i < cnt; i += 8) {
        const float4* row = (const float4*)(x + ((size_t)(bg << 12) + ord[i]) * DF);
        float4 v = row[l32];
        acc.x += v.x; acc.y += v.y; acc.z += v.z; acc.w += v.w;
    }
    part[grp][l32] = acc;
    __syncthreads();
    if (grp == 0) {
        float4 s = part[0][l32];
        #pragma unroll
        for (int g = 1; g < 8; ++g) {
            float4 p = part[g][l32];
            s.x += p.x; s.y += p.y; s.z += p.z; s.w += p.w;
        }
        ((float4*)(out + (size_t)(bg << 13) + (k << 7)))[l32] = s;
    }
}

__global__ __launch_bounds__(512) void fb_edge(
    const int* __restrict__ ei, const float* __restrict__ ew,
    const unsigned char* __restrict__ clus,
    float* __restrict__ partials, float* __restrict__ crossp,
    float* __restrict__ asqp)
{
    __shared__ float adj[KCL * KCL];
    __shared__ unsigned char cl[NPG];
    __shared__ float redc[8], redq[8];
    const int tid = threadIdx.x, bg = blockIdx.x >> 4;
    #pragma unroll
    for (int i = 0; i < 8; ++i) adj[tid + i * 512] = 0.0f;
    #pragma unroll
    for (int i = 0; i < 2; ++i)
        ((int*)cl)[tid + i * 512] = ((const int*)(clus + (size_t)bg * NPG))[tid + i * 512];
    __syncthreads();
    const int e0 = blockIdx.x * 4096;
    float csum = 0.f, qsum = 0.f;
    #pragma unroll
    for (int it = 0; it < 8; ++it) {
        const int e = e0 + it * 512 + tid;
        const int s = ei[e] & (NPG - 1);
        const int d = ei[NEDGE + e] & (NPG - 1);
        const float w = ew[e];
        const int ks = cl[s], kd = cl[d];
        atomicAdd(&adj[(ks << 6) + kd], w);
        csum += (ks == kd) ? w : 0.f;
        qsum += w * w;
    }
    #pragma unroll
    for (int off = 32; off > 0; off >>= 1) {
        csum += __shfl_down(csum, off);
        qsum += __shfl_down(qsum, off);
    }
    const int lane = tid & 63, wv = tid >> 6;
    if (lane == 0) { redc[wv] = csum; redq[wv] = qsum; }
    __syncthreads();
    if (tid == 0) {
        float cs = 0.f, qs = 0.f;
        #pragma unroll
        for (int i = 0; i < 8; ++i) { cs += redc[i]; qs += redq[i]; }
        crossp[blockIdx.x] = cs;
        asqp[blockIdx.x]   = qs;
    }
    float4* dst = (float4*)(partials + (size_t)blockIdx.x * 4096);
    const float4* src = (const float4*)adj;
    dst[tid] = src[tid];
    dst[tid + 512] = src[tid + 512];
}

__global__ __launch_bounds__(1024) void fb_reduce_finalize(
    const float* __restrict__ partials, const float* __restrict__ crossp,
    const float* __restrict__ asqp, const int* __restrict__ counts,
    float* __restrict__ out)
{
    const int tid = threadIdx.x;
    if (blockIdx.x < 64) {
        const int cell = blockIdx.x * 1024 + tid;
        const int bg = cell >> 12, j = cell & 4095;
        float s = 0.f;
        #pragma unroll
        for (int sl = 0; sl < 16; ++sl)
            s += partials[(size_t)((bg << 4) + sl) * 4096 + j];
        out[131072 + cell] = s;
        return;
    }
    __shared__ float links[16];
    const int wv = tid >> 6, lane = tid & 63;
    float c = (float)counts[(wv << 6) + lane];
    float s2 = c * c;
    #pragma unroll
    for (int off = 32; off > 0; off >>= 1) s2 += __shfl_down(s2, off);
    float cp = (lane < 16) ? crossp[(wv << 4) + lane] : 0.f;
    float ap = (lane < 16) ? asqp[(wv << 4) + lane]   : 0.f;
    #pragma unroll
    for (int off = 8; off > 0; off >>= 1) {
        cp += __shfl_down(cp, off);
        ap += __shfl_down(ap, off);
    }
    if (lane == 0) links[wv] = sqrtf(fmaxf(ap - 2.f * cp + s2, 0.f)) * (1.f / 65536.f);
    __syncthreads();
    if (tid == 0) {
        float m = 0.f;
        #pragma unroll
        for (int i = 0; i < 16; ++i) m += links[i];
        out[196608] = m * (1.f / 16.f);
        out[196609] = 0.f;
    }
    out[196610 + tid] = (float)(tid >> 6);
    if (tid < 17) out[197634 + tid] = (float)(tid << 6);
}

extern "C" void kernel_launch(void* const* d_in, const int* in_sizes, int n_in,
                              void* d_out, int out_size, void* d_ws, size_t ws_size,
                              hipStream_t stream) {
    const float* x    = (const float*)d_in[0];
    const float* W    = (const float*)d_in[1];
    const float* bias = (const float*)d_in[2];
    const float* ew   = (const float*)d_in[3];
    const float* gum  = (const float*)d_in[4];
    const int*   ei   = (const int*)  d_in[5];
    // d_in[6] = batch_ptr (int64) — unused, graphs are equal-sized

    float* out = (float*)d_out;
    char*  wsb = (char*)d_ws;

    void* args[] = {&x, &W, &bias, &ew, &gum, &ei, &out, &wsb};
    hipError_t err = hipLaunchCooperativeKernel(
        (const void*)fused_kernel, dim3(256), dim3(1024), args, 0, stream);

    if (err != hipSuccess) {
        // Fallback: proven 5-kernel pipeline, same math, same ws buffers.
        unsigned char*  clus   = (unsigned char*) (wsb + WS_CLUS);
        int*            counts = (int*)           (wsb + WS_CNT);
        int*            starts = (int*)           (wsb + WS_START);
        float*          crossp = (float*)         (wsb + WS_CROSS);
        float*          asqp   = (float*)         (wsb + WS_ASQ);
        unsigned short* order  = (unsigned short*)(wsb + WS_ORDER);
        float*          adjp   = (float*)         (wsb + WS_ADJP);

        fb_assign<<<NTOT / 64, 256, 0, stream>>>(x, W, bias, gum, clus);
        fb_sort<<<NGRAPH, 1024, 0, stream>>>(clus, counts, starts, order);
        fb_pool<<<NGRAPH * KCL, 256, 0, stream>>>(x, order, counts, starts, out);
        fb_edge<<<NGRAPH * 16, 512, 0, stream>>>(ei, ew, clus, adjp, crossp, asqp);
        fb_reduce_finalize<<<65, 1024, 0, stream>>>(adjp, crossp, asqp, counts, out);
    }
}

// Round 8
// 128.698 us; speedup vs baseline: 5.0137x; 3.6964x over previous
//
#include <hip/hip_runtime.h>

// Problem constants (fixed by the reference)
#define NGRAPH 16
#define NPG    4096
#define KCL    64
#define DF     128
#define NTOT   65536
#define NEDGE  1048576

// output layout (floats)
//   out[0,131072) | out_adj[131072,196608) | link 196608 | ent 196609
//   batch[196610,197634) | batch_ptr[197634,197651)

// ws layout (bytes) — everything plain-stored, nothing needs zeroing
#define WS_CLUS   0         // u8[65536]
#define WS_CNT    65536     // int[1024]
#define WS_START  69632     // int[1024]
#define WS_CROSS  73728     // float[256]
#define WS_ASQ    74752     // float[256]
#define WS_ORDER  75776     // u16[65536]
#define WS_ADJP   206848    // float[256][4096]

// ---------------------------------------------------------------------------
// K1: per-node argmax assignment (logits GEMM + gumbel), writes clus.
// Proven R4 design: 64-node LDS tile, 4 waves x 16 clusters, acc[16]/lane.
// ---------------------------------------------------------------------------
__global__ __launch_bounds__(256) void assign_kernel(
    const float* __restrict__ x, const float* __restrict__ W,
    const float* __restrict__ bias, const float* __restrict__ gum,
    unsigned char* __restrict__ clus)
{
    __shared__ __align__(16) float xs[64 * 132];   // 64 nodes x 128, pad 132
    __shared__ float cand_v[4][64];
    __shared__ int   cand_k[4][64];

    const int tid = threadIdx.x, wave = tid >> 6, lane = tid & 63;
    const int n0 = blockIdx.x * 64;

    {
        const float4* xg = (const float4*)(x + (size_t)n0 * DF);
        #pragma unroll
        for (int i = 0; i < 8; ++i) {
            int j4 = tid + i * 256; int j = j4 << 2;
            float4 v = xg[j4];
            *(float4*)&xs[(j >> 7) * 132 + (j & 127)] = v;
        }
    }
    __syncthreads();

    const int k0 = __builtin_amdgcn_readfirstlane(wave << 4);  // wave-uniform
    float acc[16];
    #pragma unroll
    for (int kk = 0; kk < 16; ++kk) acc[kk] = bias[k0 + kk];

    #pragma unroll 4
    for (int dc = 0; dc < 32; ++dc) {
        float4 xv = *(const float4*)&xs[lane * 132 + (dc << 2)];
        const float* wp = W + (dc << 8) + k0;      // wave-uniform -> s_load
        #pragma unroll
        for (int kk = 0; kk < 16; ++kk) {
            float a = acc[kk];
            a = fmaf(xv.x, wp[kk],        a);
            a = fmaf(xv.y, wp[64  + kk],  a);
            a = fmaf(xv.z, wp[128 + kk],  a);
            a = fmaf(xv.w, wp[192 + kk],  a);
            acc[kk] = a;
        }
    }

    // gumbel + per-wave argmax (first-max tie-break, k ascending)
    const float* gp = gum + ((size_t)(n0 + lane) << 6) + k0;
    float best = -3.4e38f; int bestk = k0;
    #pragma unroll
    for (int q = 0; q < 4; ++q) {
        float4 u = *(const float4*)(gp + (q << 2));
        float uv[4] = {u.x, u.y, u.z, u.w};
        #pragma unroll
        for (int r = 0; r < 4; ++r) {
            float g = -__logf(-__logf(uv[r]));
            float v = acc[(q << 2) + r] + g;
            if (v > best) { best = v; bestk = k0 + (q << 2) + r; }
        }
    }
    cand_v[wave][lane] = best;
    cand_k[wave][lane] = bestk;
    __syncthreads();

    if (tid < 64) {   // combine 4 waves (k-chunks ascending => global first-max)
        float bv = cand_v[0][tid]; int bk = cand_k[0][tid];
        #pragma unroll
        for (int w2 = 1; w2 < 4; ++w2) {
            float v = cand_v[w2][tid];
            if (v > bv) { bv = v; bk = cand_k[w2][tid]; }
        }
        clus[n0 + tid] = (unsigned char)bk;
    }
}

// ---------------------------------------------------------------------------
// K2: sort (blocks 0..15, one graph each)  ||  edge slices (blocks 16..271).
// Both depend only on clus; internally independent.
// ---------------------------------------------------------------------------
__global__ __launch_bounds__(1024) void sortedge_kernel(
    const unsigned char* __restrict__ clus,
    const int* __restrict__ ei, const float* __restrict__ ew,
    int* __restrict__ counts, int* __restrict__ starts,
    unsigned short* __restrict__ order,
    float* __restrict__ adjp, float* __restrict__ crossp,
    float* __restrict__ asqp)
{
    __shared__ int   hist[KCL];
    __shared__ int   offs[KCL];
    __shared__ float adj[KCL * KCL];       // 16 KB
    __shared__ unsigned char cl[NPG];      // 4 KB
    __shared__ float redc[16], redq[16];

    const int tid = threadIdx.x;

    if (blockIdx.x < 16) {
        //---------------- counting sort for graph bg ----------------
        const int bg = blockIdx.x;
        if (tid < KCL) hist[tid] = 0;
        __syncthreads();
        unsigned char c[4];
        #pragma unroll
        for (int i = 0; i < 4; ++i) {
            c[i] = clus[(bg << 12) + tid + (i << 10)];
            atomicAdd(&hist[c[i]], 1);
        }
        __syncthreads();
        if (tid < KCL) {
            int v = hist[tid], inc = v;
            #pragma unroll
            for (int off = 1; off < 64; off <<= 1) {
                int t = __shfl_up(inc, off);
                if (tid >= off) inc += t;
            }
            int excl = inc - v;
            offs[tid] = excl;
            counts[(bg << 6) + tid] = v;
            starts[(bg << 6) + tid] = excl;
        }
        __syncthreads();
        #pragma unroll
        for (int i = 0; i < 4; ++i) {
            int p = atomicAdd(&offs[c[i]], 1);
            order[(bg << 12) + p] = (unsigned short)(tid + (i << 10));
        }
    } else {
        //---------------- edge slice eb (4096 edges) ----------------
        const int eb = blockIdx.x - 16;
        const int bg = eb >> 4;
        ((float4*)adj)[tid] = make_float4(0.f, 0.f, 0.f, 0.f);
        ((int*)cl)[tid] = ((const int*)(clus + (size_t)bg * NPG))[tid];
        __syncthreads();

        const int e0 = eb << 12;
        float csum = 0.f, qsum = 0.f;
        #pragma unroll
        for (int it = 0; it < 4; ++it) {
            const int e = e0 + (it << 10) + tid;
            const int s = ei[e]         & (NPG - 1);   // graphs are 4096-aligned
            const int d = ei[NEDGE + e] & (NPG - 1);
            const float w = ew[e];
            const int ks = cl[s], kd = cl[d];
            atomicAdd(&adj[(ks << 6) + kd], w);
            csum += (ks == kd) ? w : 0.f;
            qsum += w * w;
        }
        #pragma unroll
        for (int off = 32; off > 0; off >>= 1) {
            csum += __shfl_down(csum, off);
            qsum += __shfl_down(qsum, off);
        }
        const int lane = tid & 63, wv = tid >> 6;
        if (lane == 0) { redc[wv] = csum; redq[wv] = qsum; }
        __syncthreads();   // also guarantees all LDS atomics into adj are done
        if (tid == 0) {
            float cs = 0.f, qs = 0.f;
            #pragma unroll
            for (int i = 0; i < 16; ++i) { cs += redc[i]; qs += redq[i]; }
            crossp[eb] = cs;
            asqp[eb]   = qs;
        }
        ((float4*)(adjp + ((size_t)eb << 12)))[tid] = ((const float4*)adj)[tid];
    }
}

// ---------------------------------------------------------------------------
// K3: pool (blocks 0..1023)  ||  adj-reduce (1024..1279)  ||  finalize (1280).
// All depend on K2 outputs; internally independent.
// ---------------------------------------------------------------------------
__global__ __launch_bounds__(256) void poolreduce_kernel(
    const float* __restrict__ x, const unsigned short* __restrict__ order,
    const int* __restrict__ counts, const int* __restrict__ starts,
    const float* __restrict__ adjp, const float* __restrict__ crossp,
    const float* __restrict__ asqp, float* __restrict__ out)
{
    __shared__ unsigned short ord[NPG];
    __shared__ float4 part[8][32];
    __shared__ float links[16];

    const int tid = threadIdx.x;
    const int blk = blockIdx.x;

    if (blk < 1024) {
        //---------------- segment-sum pooling for (graph, cluster) ----------
        const int bg = blk >> 6, k = blk & 63;
        const int cnt = counts[blk], start = starts[blk];
        for (int i = tid; i < cnt; i += 256)
            ord[i] = order[(bg << 12) + start + i];
        __syncthreads();
        const int grp = tid >> 5, l32 = tid & 31;
        float4 acc = {0.f, 0.f, 0.f, 0.f};
        for (int i = grp; i < cnt; i += 8) {
            const float4* row = (const float4*)(x + (((size_t)(bg << 12) + ord[i]) << 7));
            float4 v = row[l32];
            acc.x += v.x; acc.y += v.y; acc.z += v.z; acc.w += v.w;
        }
        part[grp][l32] = acc;
        __syncthreads();
        if (grp == 0) {
            float4 s = part[0][l32];
            #pragma unroll
            for (int g = 1; g < 8; ++g) {
                float4 p = part[g][l32];
                s.x += p.x; s.y += p.y; s.z += p.z; s.w += p.w;
            }
            ((float4*)(out + ((size_t)(bg << 13) + (k << 7))))[l32] = s;
        }
    } else if (blk < 1280) {
        //---------------- out_adj: reduce the 16 slice-partials -------------
        const int cell = ((blk - 1024) << 8) + tid;   // 0..65535
        const int bg = cell >> 12, j = cell & 4095;
        float s = 0.f;
        #pragma unroll
        for (int sl = 0; sl < 16; ++sl)
            s += adjp[(size_t)(((bg << 4) + sl) << 12) + j];
        out[131072 + cell] = s;
    } else {
        //---------------- losses + constant outputs -------------------------
        if (tid < 16) {
            const int bg = tid;
            float s2 = 0.f;
            #pragma unroll 8
            for (int k = 0; k < 64; ++k) {
                float c = (float)counts[(bg << 6) + k];
                s2 = fmaf(c, c, s2);
            }
            float cs = 0.f, as = 0.f;
            #pragma unroll
            for (int sl = 0; sl < 16; ++sl) {
                cs += crossp[(bg << 4) + sl];
                as += asqp[(bg << 4) + sl];
            }
            links[bg] = sqrtf(fmaxf(as - 2.f * cs + s2, 0.f)) * (1.f / 65536.f);
        }
        __syncthreads();
        if (tid == 0) {
            float m = 0.f;
            #pragma unroll
            for (int i = 0; i < 16; ++i) m += links[i];
            out[196608] = m * (1.f / 16.f);   // link_loss
            out[196609] = 0.f;                // entropy_loss (exact 0 for one-hot)
        }
        #pragma unroll
        for (int r = 0; r < 4; ++r) {
            int i = tid + (r << 8);
            out[196610 + i] = (float)(i >> 6);            // batch
        }
        if (tid < 17) out[197634 + tid] = (float)(tid << 6);  // batch_ptr_out
    }
}

extern "C" void kernel_launch(void* const* d_in, const int* in_sizes, int n_in,
                              void* d_out, int out_size, void* d_ws, size_t ws_size,
                              hipStream_t stream) {
    const float* x    = (const float*)d_in[0];
    const float* W    = (const float*)d_in[1];
    const float* bias = (const float*)d_in[2];
    const float* ew   = (const float*)d_in[3];
    const float* gum  = (const float*)d_in[4];
    const int*   ei   = (const int*)  d_in[5];
    // d_in[6] = batch_ptr (int64) — unused, graphs are equal-sized

    float* out = (float*)d_out;
    char*  wsb = (char*)d_ws;

    unsigned char*  clus   = (unsigned char*) (wsb + WS_CLUS);
    int*            counts = (int*)           (wsb + WS_CNT);
    int*            starts = (int*)           (wsb + WS_START);
    float*          crossp = (float*)         (wsb + WS_CROSS);
    float*          asqp   = (float*)         (wsb + WS_ASQ);
    unsigned short* order  = (unsigned short*)(wsb + WS_ORDER);
    float*          adjp   = (float*)         (wsb + WS_ADJP);

    assign_kernel<<<NTOT / 64, 256, 0, stream>>>(x, W, bias, gum, clus);

    sortedge_kernel<<<16 + 256, 1024, 0, stream>>>(
        clus, ei, ew, counts, starts, order, adjp, crossp, asqp);

    poolreduce_kernel<<<1024 + 256 + 1, 256, 0, stream>>>(
        x, order, counts, starts, adjp, crossp, asqp, out);
}